// Round 8
// baseline (73.286 us; speedup 1.0000x reference)
//
#include <hip/hip_runtime.h>
#include <math.h>

#define B 2048
#define D 64
#define IT 16           // i-rows per main wave
#define NCH 32          // j-chunks for main role
#define CJ (B / NCH)    // 64
#define NC2 16          // j-chunks for the MFMA/LSE role

typedef float v2f  __attribute__((ext_vector_type(2)));
typedef short bf16x8 __attribute__((ext_vector_type(8)));
typedef float f32x4  __attribute__((ext_vector_type(4)));

static __device__ __forceinline__ float exp2fast(float x) { return __builtin_amdgcn_exp2f(x); }
static __device__ __forceinline__ float log2fast(float x) { return __builtin_amdgcn_logf(x); }
static __device__ __forceinline__ unsigned short f2bf(float x) {
    unsigned u = __float_as_uint(x);
    u += 0x7fff + ((u >> 16) & 1);          // RNE; inputs are finite
    return (unsigned short)(u >> 16);
}

// ---------------------------------------------------------------------------
// Kernel 1: per-(j,d) constants (log2 units):  lp2 = h*z^2 + g*z + q
//   h = -0.5*log2e*exp(-lv), g = -2*mu*h, q = mu^2*h + c,
//   c = -0.5*log2e*(lv + ln 2pi)
// Outputs: pack4 (fp32, main role), Zx/Wt (bf16 MFMA operands), QQ[j]=sum_d q,
// acc zeroed, kl block-reduced -> 1 atomic.
// ---------------------------------------------------------------------------
__global__ __launch_bounds__(256) void k_pre(
    const float* __restrict__ kl, const float* __restrict__ zm,
    const float* __restrict__ zlv, const float* __restrict__ zs,
    float4* __restrict__ pack4, unsigned short* __restrict__ Zx,
    unsigned short* __restrict__ Wt, float* __restrict__ QQ,
    float* __restrict__ acc, float* __restrict__ out)
{
    const float LOG2E   = 1.4426950408889634f;
    const float LOG_2PI = 1.8378770664093453f;
    __shared__ float red[4];
    int wv = threadIdx.x >> 6, d = threadIdx.x & 63;
    int j = blockIdx.x * 4 + wv;
    int idx = j * D + d;
    acc[idx] = 0.0f;
    float lv = zlv[idx];
    float mu = zm[idx];
    float zz = zs[idx];
    float is = exp2fast(-LOG2E * lv);            // e^{-lv}
    float h  = -0.5f * LOG2E * is;
    float cv = -0.5f * LOG2E * (lv + LOG_2PI);
    float g  = -2.0f * mu * h;
    float q  = fmaf(mu * mu, h, cv);
    pack4[idx] = make_float4(h, g, q, 0.0f);
    Wt[j * 128 + d]      = f2bf(h);
    Wt[j * 128 + 64 + d] = f2bf(g);
    Zx[j * 128 + d]      = f2bf(zz * zz);
    Zx[j * 128 + 64 + d] = f2bf(zz);

    float qs = q, ks = kl[idx];
#pragma unroll
    for (int off = 32; off; off >>= 1) {
        qs += __shfl_xor(qs, off);
        ks += __shfl_xor(ks, off);
    }
    if (d == 0) { QQ[j] = qs; red[wv] = ks; }
    __syncthreads();
    if (threadIdx.x == 0)
        atomicAdd(out, red[0] + red[1] + red[2] + red[3]);  // kl_loss
}

// ---------------------------------------------------------------------------
// Role A (main): acc[i][d] += sum_j 2^(h z^2 + g z + q); wave = IT=16 rows i
// (8 float2 pairs), one 64-j chunk, lanes own d. Packed fp32 FMA + exp2.
// ---------------------------------------------------------------------------
static __device__ __forceinline__ void role_main(
    int chunk, int igroup, const float* __restrict__ z,
    const float4* __restrict__ pack4, float* __restrict__ acc)
{
    int lane = threadIdx.x & 63;
    int i0   = igroup * IT;
    int j0   = chunk * CJ;

    v2f zrp[IT / 2], zr2p[IT / 2], ap[IT / 2];
#pragma unroll
    for (int kp = 0; kp < IT / 2; ++kp) {
        float za = z[(i0 + 2 * kp) * D + lane];
        float zb = z[(i0 + 2 * kp + 1) * D + lane];
        zrp[kp]  = (v2f){za, zb};
        zr2p[kp] = (v2f){za * za, zb * zb};
        ap[kp]   = (v2f){0.0f, 0.0f};
    }

#pragma unroll 2
    for (int j = j0; j < j0 + CJ; ++j) {
        float4 p = pack4[j * D + lane];
        v2f hh = (v2f){p.x, p.x};
        v2f gg = (v2f){p.y, p.y};
        v2f qq = (v2f){p.z, p.z};
#pragma unroll
        for (int kp = 0; kp < IT / 2; ++kp) {
            v2f arg = zr2p[kp] * hh + (zrp[kp] * gg + qq);  // 2x v_pk_fma_f32
            v2f e;
            e.x = exp2fast(arg.x);
            e.y = exp2fast(arg.y);
            ap[kp] += e;                                    // v_pk_add_f32
        }
    }
#pragma unroll
    for (int kp = 0; kp < IT / 2; ++kp) {
        atomicAdd(&acc[(i0 + 2 * kp) * D + lane], ap[kp].x);
        atomicAdd(&acc[(i0 + 2 * kp + 1) * D + lane], ap[kp].y);
    }
}

// ---------------------------------------------------------------------------
// Role B (lse): s2[i][j] = QQ_j + sum_k Zx[i][k]*Wt[j][k] via 16x16x32 bf16
// MFMA, row-LSE over j fused in epilogue. One wave = 16-i block x 128-j chunk.
// C/D: col = lane&15 (j), row = (lane>>4)*4 + reg (i)  [m89-verified].
// ---------------------------------------------------------------------------
static __device__ __forceinline__ void role_lse(
    int lw, const unsigned short* __restrict__ Zx,
    const unsigned short* __restrict__ Wt, const float* __restrict__ QQ,
    float* __restrict__ wsM, float* __restrict__ wsL)
{
    int lane  = threadIdx.x & 63;
    int i0    = (lw >> 4) * 16;
    int chunk = lw & 15;               // 0..15
    int jbase = chunk * 128;
    int r16 = lane & 15, kg = lane >> 4;

    const bf16x8* Za = (const bf16x8*)(Zx + (size_t)(i0 + r16) * 128 + kg * 8);
    bf16x8 a[4];
#pragma unroll
    for (int s = 0; s < 4; ++s) a[s] = Za[s * 4];   // stride 32 bf16 per K-step

    float m[4], l[4];
#pragma unroll
    for (int r = 0; r < 4; ++r) { m[r] = -3.0e38f; l[r] = 0.0f; }

    for (int t = 0; t < 8; ++t) {
        int j = jbase + t * 16 + r16;
        const bf16x8* Wb = (const bf16x8*)(Wt + (size_t)j * 128 + kg * 8);
        f32x4 c = (f32x4){0.0f, 0.0f, 0.0f, 0.0f};
#pragma unroll
        for (int s = 0; s < 4; ++s)
            c = __builtin_amdgcn_mfma_f32_16x16x32_bf16(a[s], Wb[s * 4], c, 0, 0, 0);
        float qq = QQ[j];
#pragma unroll
        for (int r = 0; r < 4; ++r) {
            float val = c[r] + qq;
            float delta = val - m[r];
            float e = exp2fast(-fabsf(delta));
            l[r] = (delta <= 0.0f) ? (l[r] + e) : fmaf(l[r], e, 1.0f);
            m[r] = fmaxf(m[r], val);
        }
    }
#pragma unroll
    for (int off = 8; off; off >>= 1) {
#pragma unroll
        for (int r = 0; r < 4; ++r) {
            float m2 = __shfl_xor(m[r], off);
            float l2 = __shfl_xor(l[r], off);
            float M  = fmaxf(m[r], m2);
            l[r] = fmaf(l[r], exp2fast(m[r] - M), l2 * exp2fast(m2 - M));
            m[r] = M;
        }
    }
    if (r16 == 0) {
#pragma unroll
        for (int r = 0; r < 4; ++r) {
            int i = i0 + kg * 4 + r;
            wsM[i * NC2 + chunk] = m[r];
            wsL[i * NC2 + chunk] = l[r];
        }
    }
}

// ---------------------------------------------------------------------------
// Kernel 2: wave-role mega-kernel. 2048 UNIFORM blocks x 192 threads:
//   waves 0,1 -> main role (4096 waves; both waves share chunk = bid&31 for
//               L1/L2 reuse; igroup = (bid>>5)*2 + wv)
//   wave 2    -> lse role  (2048 waves; lw = bid)
// Uniform blocks = even retire = dense occupancy start to finish.
// ---------------------------------------------------------------------------
__global__ __launch_bounds__(192) void k_mega(
    const float* __restrict__ z, const float4* __restrict__ pack4,
    float* __restrict__ acc, const unsigned short* __restrict__ Zx,
    const unsigned short* __restrict__ Wt, const float* __restrict__ QQ,
    float* __restrict__ wsM, float* __restrict__ wsL)
{
    int wv = threadIdx.x >> 6;
    int bid = blockIdx.x;
    if (wv == 2)
        role_lse(bid, Zx, Wt, QQ, wsM, wsL);
    else
        role_main(bid & 31, (bid >> 5) * 2 + wv, z, pack4, acc);
}

// ---------------------------------------------------------------------------
// Kernel 3: per-i finalization, one wave per i.
// ---------------------------------------------------------------------------
__global__ __launch_bounds__(256) void k_fin(
    const float* __restrict__ acc, const float* __restrict__ wsM,
    const float* __restrict__ wsL, float* __restrict__ out)
{
    const float LN2 = 0.6931471805599453f;
    __shared__ float red[4];
    int lane = threadIdx.x & 63;
    int wv   = threadIdx.x >> 6;
    int i    = blockIdx.x * 4 + wv;

    float lqp2 = log2fast(acc[i * D + lane]);
#pragma unroll
    for (int off = 32; off; off >>= 1) lqp2 += __shfl_xor(lqp2, off);

    float m = -3.0e38f, l = 0.0f;
    if (lane < NC2) { m = wsM[i * NC2 + lane]; l = wsL[i * NC2 + lane]; }
#pragma unroll
    for (int off = 32; off; off >>= 1) {
        float m2 = __shfl_xor(m, off);
        float l2 = __shfl_xor(l, off);
        float M  = fmaxf(m, m2);
        l = fmaf(l, exp2fast(m - M), l2 * exp2fast(m2 - M));
        m = M;
    }

    if (lane == 0)
        red[wv] = (m + log2fast(l) - lqp2) * LN2;
    __syncthreads();
    if (threadIdx.x == 0)
        atomicAdd(out, (red[0] + red[1] + red[2] + red[3]) * (5.0f / 2048.0f));
}

// ---------------------------------------------------------------------------
extern "C" void kernel_launch(void* const* d_in, const int* in_sizes, int n_in,
                              void* d_out, int out_size, void* d_ws, size_t ws_size,
                              hipStream_t stream)
{
    const float* kl  = (const float*)d_in[0];
    const float* zm  = (const float*)d_in[1];
    const float* zlv = (const float*)d_in[2];
    const float* zs  = (const float*)d_in[3];
    float* out = (float*)d_out;
    float* ws  = (float*)d_ws;

    // workspace layout (floats)
    float4*         pack4 = (float4*)ws;                         // 4*B*D
    unsigned short* Zx    = (unsigned short*)(ws + 4 * B * D);   // B*128 u16
    unsigned short* Wt    = (unsigned short*)(ws + 4 * B * D + (B * 128) / 2);
    float*          QQ    = ws + 4 * B * D + B * 128;            // B
    float*          wsM   = QQ + B;                              // B*NC2
    float*          wsL   = wsM + (size_t)B * NC2;               // B*NC2
    float*          acc   = wsL + (size_t)B * NC2;               // B*D

    hipMemsetAsync(d_out, 0, sizeof(float), stream);
    k_pre<<<B / 4, 256, 0, stream>>>(kl, zm, zlv, zs, pack4, Zx, Wt, QQ, acc, out);
    k_mega<<<2048, 192, 0, stream>>>(zs, pack4, acc, Zx, Wt, QQ, wsM, wsL);
    k_fin<<<B / 4, 256, 0, stream>>>(acc, wsM, wsL, out);
}